// Round 6
// baseline (1557.485 us; speedup 1.0000x reference)
//
#include <hip/hip_runtime.h>
#include <hip/hip_bf16.h>
#include <stdint.h>

#define DEV __device__ __forceinline__

constexpr int B_ = 4, S_ = 2048, D_ = 1024, H_ = 16, HD_ = 64;
constexpr int BH_ = B_ * H_;   // 64
constexpr int BS_ = B_ * S_;   // 8192

typedef __attribute__((ext_vector_type(8))) short bf16x8;
typedef __attribute__((ext_vector_type(4))) float f32x4;

// log2(e)/64 : scores*SCL fed to exp2 == exp(scores/64)
constexpr float SCL = 0.022542110013890053f;

DEV float fast_exp2(float x) { return __builtin_amdgcn_exp2f(x); }

DEV uint16_t f2bf(float f) {
    union { float f; uint32_t u; } v; v.f = f;
    return (uint16_t)((v.u + 0x7fffu + ((v.u >> 16) & 1u)) >> 16);
}

DEV uint16_t f2bf_fast(float f) {
    __hip_bfloat16 h = __float2bfloat16(f);
    uint16_t u; __builtin_memcpy(&u, &h, 2);
    return u;
}

DEV f32x4 mfma16(bf16x8 a, bf16x8 b, f32x4 c) {
    return __builtin_amdgcn_mfma_f32_16x16x32_bf16(a, b, c, 0, 0, 0);
}

// LDS-only barrier: waits ds ops, does NOT drain vmcnt -> prefetched global
// loads stay in flight across it (rule-18 sched fences included).
DEV void barrier_lds() {
    __builtin_amdgcn_sched_barrier(0);
    asm volatile("s_waitcnt lgkmcnt(0)" ::: "memory");
    __builtin_amdgcn_s_barrier();
    __builtin_amdgcn_sched_barrier(0);
}

// ---------------------------------------------------------------------------
// Prep: bf16-transpose weights + bf16 convert x.
// ---------------------------------------------------------------------------
__global__ __launch_bounds__(256) void k_prep(
    const float* __restrict__ Win, const float* __restrict__ Wout,
    const float* __restrict__ Wa, const float* __restrict__ x,
    uint16_t* __restrict__ WtIn, uint16_t* __restrict__ WtOut,
    uint16_t* __restrict__ WtA, uint16_t* __restrict__ xb) {
    int stride = gridDim.x * blockDim.x;
    int idx = blockIdx.x * blockDim.x + threadIdx.x;
    for (int i = idx; i < BS_ * D_ / 4; i += stride) {
        float4 v = reinterpret_cast<const float4*>(x)[i];
        ushort4 o;
        o.x = f2bf(v.x); o.y = f2bf(v.y); o.z = f2bf(v.z); o.w = f2bf(v.w);
        reinterpret_cast<ushort4*>(xb)[i] = o;
    }
    for (int i = idx; i < D_ * D_; i += stride) {
        int n = i / D_, k = i % D_;
        WtIn[i]  = f2bf(Win[(size_t)k * D_ + n]);
        WtOut[i] = f2bf(Wout[(size_t)k * D_ + n]);
    }
    for (int i = idx; i < H_ * HD_ * HD_; i += stride) {
        int h = i / (HD_ * HD_);
        int r = i % (HD_ * HD_);
        int e = r / HD_, d = r % HD_;
        WtA[i] = f2bf(Wa[((size_t)h * HD_ + d) * HD_ + e]);
    }
}

// ---------------------------------------------------------------------------
// in_proj: h = xb @ W_in + b_in   (M=8192, N=1024, K=1024)
// 1-D grid 2048, XCD-swizzled: XCD x owns col-panels {2x,2x+1} (B-panel L2).
// ---------------------------------------------------------------------------
__global__ __launch_bounds__(256) void k_gemm_in(
    const uint16_t* __restrict__ xb, const uint16_t* __restrict__ WtIn,
    const float* __restrict__ b_in, uint16_t* __restrict__ hb) {
    const int wave = threadIdx.x >> 6, lane = threadIdx.x & 63;
    const int lhi = lane >> 4, llo = lane & 15;
    const int L = blockIdx.x, xcd = L & 7, slot = L >> 3;
    const int col0 = ((xcd << 1) | (slot & 1)) * 64;
    const int row0 = (slot >> 1) * 64 + wave * 16;

    f32x4 acc[4] = {};
    const uint16_t* xrow = xb + (size_t)(row0 + llo) * D_;
    for (int kc = 0; kc < D_ / 32; ++kc) {
        const int k0 = kc * 32 + lhi * 8;
        bf16x8 a = *reinterpret_cast<const bf16x8*>(xrow + k0);
#pragma unroll
        for (int nt = 0; nt < 4; ++nt) {
            const uint16_t* bp = WtIn + (size_t)(col0 + nt * 16 + llo) * D_ + k0;
            bf16x8 b = *reinterpret_cast<const bf16x8*>(bp);
            acc[nt] = mfma16(a, b, acc[nt]);
        }
    }
#pragma unroll
    for (int nt = 0; nt < 4; ++nt) {
        const int c = col0 + nt * 16 + llo;
        const float bias = b_in[c];
        const int bhcol = c >> 6, d = c & 63;
#pragma unroll
        for (int r = 0; r < 4; ++r) {
            const int m = row0 + lhi * 4 + r;
            const int b_ = m >> 11, s = m & 2047;
            hb[((size_t)(b_ * H_ + bhcol) * S_ + s) * HD_ + d] = f2bf(acc[nt][r] + bias);
        }
    }
}

// ---------------------------------------------------------------------------
// Transpose hb [bh][s][d] -> hbT [bh][d][s]
// ---------------------------------------------------------------------------
__global__ __launch_bounds__(256) void k_transpose(
    const uint16_t* __restrict__ hb, uint16_t* __restrict__ hbT) {
    __shared__ uint16_t tile[64][72];
    const int st = blockIdx.x, bh = blockIdx.y;
    const int s0 = st * 64;
    const int t = threadIdx.x;
    {
        const int r = t >> 2, c0 = (t & 3) * 16;
        const uint16_t* src = hb + ((size_t)bh * S_ + s0 + r) * HD_ + c0;
        *reinterpret_cast<bf16x8*>(&tile[r][c0])     = *reinterpret_cast<const bf16x8*>(src);
        *reinterpret_cast<bf16x8*>(&tile[r][c0 + 8]) = *reinterpret_cast<const bf16x8*>(src + 8);
    }
    __syncthreads();
    {
        const int d = t >> 2, c0 = (t & 3) * 16;
        uint16_t tmp[16];
#pragma unroll
        for (int j = 0; j < 16; ++j) tmp[j] = tile[c0 + j][d];
        uint16_t* dst = hbT + ((size_t)bh * HD_ + d) * S_ + s0 + c0;
        *reinterpret_cast<bf16x8*>(dst)     = *reinterpret_cast<const bf16x8*>(tmp);
        *reinterpret_cast<bf16x8*>(dst + 8) = *reinterpret_cast<const bf16x8*>(tmp + 8);
    }
}

// ---------------------------------------------------------------------------
// q-proj: q[bh][s][e] = sum_d h[bh][s][d] * W_attn[h][d][e]
// ---------------------------------------------------------------------------
__global__ __launch_bounds__(256) void k_gemm_q(
    const uint16_t* __restrict__ hb, const uint16_t* __restrict__ WtA,
    uint16_t* __restrict__ qb) {
    const int wave = threadIdx.x >> 6, lane = threadIdx.x & 63;
    const int lhi = lane >> 4, llo = lane & 15;
    const int bh = blockIdx.y;
    const int h = bh & (H_ - 1);
    const int row0 = blockIdx.x * 64 + wave * 16;

    const uint16_t* hrow = hb + ((size_t)bh * S_ + row0 + llo) * HD_;
    f32x4 acc[4] = {};
#pragma unroll
    for (int kc = 0; kc < 2; ++kc) {
        const int k0 = kc * 32 + lhi * 8;
        bf16x8 a = *reinterpret_cast<const bf16x8*>(hrow + k0);
#pragma unroll
        for (int nt = 0; nt < 4; ++nt) {
            bf16x8 b = *reinterpret_cast<const bf16x8*>(
                WtA + ((size_t)h * HD_ + nt * 16 + llo) * HD_ + k0);
            acc[nt] = mfma16(a, b, acc[nt]);
        }
    }
#pragma unroll
    for (int nt = 0; nt < 4; ++nt) {
        const int e = nt * 16 + llo;
#pragma unroll
        for (int r = 0; r < 4; ++r) {
            const int s = row0 + lhi * 4 + r;
            qb[((size_t)bh * S_ + s) * HD_ + e] = f2bf(acc[nt][r]);
        }
    }
}

// ---------------------------------------------------------------------------
// Fused attention v2: LDS-staged h tiles, double-buffered raw-barrier
// pipeline, XCD-swizzled bh assignment, nontemporal w stores, fused PV.
// Block = 4 waves = 64 q-rows of one bh. LDS stride 72 (144B) gives
// bank-quad-uniform ds_read_b128 (structurally optimal 8 dword/bank).
// ---------------------------------------------------------------------------
__global__ __launch_bounds__(256) void k_attn_fused(
    const uint16_t* __restrict__ qb, const uint16_t* __restrict__ hb,
    const uint16_t* __restrict__ hbT, float* __restrict__ w_out,
    uint16_t* __restrict__ pvb) {
    __shared__ uint16_t hs[2][64 * 72];   // staged h chunk (double buffer)
    __shared__ uint16_t wb[64 * 72];      // w tile, wave-private 16-row bands

    const int tid = threadIdx.x;
    const int wave = tid >> 6, lane = tid & 63;
    const int lhi = lane >> 4, llo = lane & 15;

    // XCD swizzle: XCD x owns bh in [8x, 8x+8) -> h/hbT working set ~4MB = L2
    const int L = blockIdx.x;
    const int xcd = L & 7, slot = L >> 3;
    const int bh = (xcd << 3) | (slot >> 5);
    const int row0 = (slot & 31) * 64;
    const int wrow0 = wave * 16;

    const uint16_t* hbase  = hb  + (size_t)bh * S_ * HD_;
    const uint16_t* hTbase = hbT + (size_t)bh * HD_ * S_;

    const uint16_t* qrow = qb + ((size_t)bh * S_ + row0 + wrow0 + llo) * HD_;
    const bf16x8 a0 = *reinterpret_cast<const bf16x8*>(qrow + lhi * 8);
    const bf16x8 a1 = *reinterpret_cast<const bf16x8*>(qrow + 32 + lhi * 8);

    // cooperative staging coords: thread covers rows tid>>3 and 32+(tid>>3)
    const int soff = (tid >> 3) * 72 + (tid & 7) * 8;

    auto stage_load = [&](int tch, bf16x8& r0, bf16x8& r1) {
        const uint16_t* src = hbase + (size_t)tch * 4096 + tid * 8;
        r0 = *reinterpret_cast<const bf16x8*>(src);
        r1 = *reinterpret_cast<const bf16x8*>(src + 2048);
    };
    auto stage_write = [&](int buf, bf16x8 r0, bf16x8 r1) {
        uint16_t* d = &hs[buf][soff];
        *reinterpret_cast<bf16x8*>(d) = r0;
        *reinterpret_cast<bf16x8*>(d + 32 * 72) = r1;
    };
    auto score2 = [&](int buf, int ct) -> f32x4 {
        const uint16_t* p = &hs[buf][(ct * 16 + llo) * 72 + lhi * 8];
        bf16x8 b0 = *reinterpret_cast<const bf16x8*>(p);
        bf16x8 b1 = *reinterpret_cast<const bf16x8*>(p + 32);
        f32x4 acc = {};
        acc = mfma16(a0, b0, acc);
        acc = mfma16(a1, b1, acc);
        return acc;
    };

    // ================= pass 1: row sums of exp =================
    float sume[4] = {0.f, 0.f, 0.f, 0.f};
    {
        bf16x8 rA0, rA1, rB0, rB1;
        stage_load(0, rA0, rA1);
        for (int tt = 0; tt < 32; tt += 2) {
            stage_write(0, rA0, rA1);
            stage_load(tt + 1, rB0, rB1);
            barrier_lds();
#pragma unroll
            for (int ct = 0; ct < 4; ++ct) {
                f32x4 acc = score2(0, ct);
#pragma unroll
                for (int r = 0; r < 4; ++r) sume[r] += fast_exp2(acc[r] * SCL);
            }
            stage_write(1, rB0, rB1);
            if (tt + 2 < 32) stage_load(tt + 2, rA0, rA1);
            barrier_lds();
#pragma unroll
            for (int ct = 0; ct < 4; ++ct) {
                f32x4 acc = score2(1, ct);
#pragma unroll
                for (int r = 0; r < 4; ++r) sume[r] += fast_exp2(acc[r] * SCL);
            }
        }
    }
    float inv[4];
#pragma unroll
    for (int r = 0; r < 4; ++r) {
        float v = sume[r];
        v += __shfl_xor(v, 1); v += __shfl_xor(v, 2);
        v += __shfl_xor(v, 4); v += __shfl_xor(v, 8);
        inv[r] = 1.0f / v;
    }

    // ================= pass 2: w tiles (NT store) + PV =================
    f32x4 pv[4] = {};
    const int srr = wrow0 + (lane >> 2), sc0 = (lane & 3) * 16;
    float* wdst_base = w_out + ((size_t)bh * S_ + row0 + srr) * S_ + sc0;

    auto body2 = [&](int buf, int tch) {
        const int t0 = tch * 64;
        // scores -> normalized bf16 w into wave-private wb rows
#pragma unroll
        for (int ct = 0; ct < 4; ++ct) {
            f32x4 acc = score2(buf, ct);
#pragma unroll
            for (int r = 0; r < 4; ++r) {
                float wv = fast_exp2(acc[r] * SCL) * inv[r];
                wb[(wrow0 + lhi * 4 + r) * 72 + ct * 16 + llo] = f2bf_fast(wv);
            }
        }
        // coalesced nontemporal fp32 store of wave's own 16x64 w rows
        {
            const uint16_t* wsrc = &wb[srr * 72 + sc0];
            bf16x8 v0 = *reinterpret_cast<const bf16x8*>(wsrc);
            bf16x8 v1 = *reinterpret_cast<const bf16x8*>(wsrc + 8);
            float* dst = wdst_base + t0;
            f32x4 f0, f1, f2, f3;
#pragma unroll
            for (int j = 0; j < 4; ++j) {
                f0[j] = __uint_as_float(((uint32_t)(uint16_t)v0[j]) << 16);
                f1[j] = __uint_as_float(((uint32_t)(uint16_t)v0[4 + j]) << 16);
                f2[j] = __uint_as_float(((uint32_t)(uint16_t)v1[j]) << 16);
                f3[j] = __uint_as_float(((uint32_t)(uint16_t)v1[4 + j]) << 16);
            }
            __builtin_nontemporal_store(f0, reinterpret_cast<f32x4*>(dst));
            __builtin_nontemporal_store(f1, reinterpret_cast<f32x4*>(dst + 4));
            __builtin_nontemporal_store(f2, reinterpret_cast<f32x4*>(dst + 8));
            __builtin_nontemporal_store(f3, reinterpret_cast<f32x4*>(dst + 12));
        }
        // PV accumulation: A = wave's wb rows, B = hbT (L2-resident)
#pragma unroll
        for (int kk = 0; kk < 2; ++kk) {
            bf16x8 a = *reinterpret_cast<const bf16x8*>(
                &wb[(wrow0 + llo) * 72 + kk * 32 + lhi * 8]);
#pragma unroll
            for (int dt = 0; dt < 4; ++dt) {
                bf16x8 b = *reinterpret_cast<const bf16x8*>(
                    hTbase + (size_t)(dt * 16 + llo) * S_ + t0 + kk * 32 + lhi * 8);
                pv[dt] = mfma16(a, b, pv[dt]);
            }
        }
    };

    {
        bf16x8 rA0, rA1, rB0, rB1;
        stage_load(0, rA0, rA1);
        for (int tt = 0; tt < 32; tt += 2) {
            stage_write(0, rA0, rA1);
            stage_load(tt + 1, rB0, rB1);
            barrier_lds();
            body2(0, tt);
            stage_write(1, rB0, rB1);
            if (tt + 2 < 32) stage_load(tt + 2, rA0, rA1);
            barrier_lds();
            body2(1, tt + 1);
        }
    }

    // epilogue: store pv bf16 into [B][S][D] layout
    const int b_ = bh >> 4, h = bh & (H_ - 1);
#pragma unroll
    for (int dt = 0; dt < 4; ++dt) {
        const int d = dt * 16 + llo;
#pragma unroll
        for (int r = 0; r < 4; ++r) {
            const int s = row0 + wrow0 + lhi * 4 + r;
            pvb[((size_t)(b_ * S_ + s)) * D_ + h * HD_ + d] = f2bf(pv[dt][r]);
        }
    }
}

// ---------------------------------------------------------------------------
// out_proj: out = pv @ W_out + b_out  (fp32 out, NT stores, XCD swizzle)
// ---------------------------------------------------------------------------
__global__ __launch_bounds__(256) void k_gemm_out(
    const uint16_t* __restrict__ pvb, const uint16_t* __restrict__ WtOut,
    const float* __restrict__ b_out, float* __restrict__ out) {
    const int wave = threadIdx.x >> 6, lane = threadIdx.x & 63;
    const int lhi = lane >> 4, llo = lane & 15;
    const int L = blockIdx.x, xcd = L & 7, slot = L >> 3;
    const int col0 = ((xcd << 1) | (slot & 1)) * 64;
    const int row0 = (slot >> 1) * 64 + wave * 16;

    const uint16_t* prow = pvb + (size_t)(row0 + llo) * D_;
    f32x4 acc[4] = {};
    for (int kc = 0; kc < D_ / 32; ++kc) {
        const int k0 = kc * 32 + lhi * 8;
        bf16x8 a = *reinterpret_cast<const bf16x8*>(prow + k0);
#pragma unroll
        for (int nt = 0; nt < 4; ++nt) {
            bf16x8 b = *reinterpret_cast<const bf16x8*>(
                WtOut + (size_t)(col0 + nt * 16 + llo) * D_ + k0);
            acc[nt] = mfma16(a, b, acc[nt]);
        }
    }
#pragma unroll
    for (int nt = 0; nt < 4; ++nt) {
        const int c = col0 + nt * 16 + llo;
        const float bias = b_out[c];
#pragma unroll
        for (int r = 0; r < 4; ++r) {
            __builtin_nontemporal_store(
                acc[nt][r] + bias, out + (size_t)(row0 + lhi * 4 + r) * D_ + c);
        }
    }
}

// ---------------------------------------------------------------------------
extern "C" void kernel_launch(void* const* d_in, const int* in_sizes, int n_in,
                              void* d_out, int out_size, void* d_ws, size_t ws_size,
                              hipStream_t stream) {
    const float* x      = (const float*)d_in[0];
    const float* W_attn = (const float*)d_in[1];
    const float* W_in   = (const float*)d_in[2];
    const float* b_in   = (const float*)d_in[3];
    const float* W_out  = (const float*)d_in[4];
    const float* b_out  = (const float*)d_in[5];

    float* out   = (float*)d_out;                       // [B,S,D]
    float* w_out = out + (size_t)BS_ * D_;              // [B,H,S,S]

    uint8_t* ws = (uint8_t*)d_ws;
    auto carve = [&](size_t elems) {
        uint16_t* p = (uint16_t*)ws;
        ws += ((elems * sizeof(uint16_t) + 255) / 256) * 256;
        return p;
    };
    uint16_t* WtIn  = carve((size_t)D_ * D_);
    uint16_t* WtOut = carve((size_t)D_ * D_);
    uint16_t* WtA   = carve((size_t)H_ * HD_ * HD_);
    uint16_t* xb    = carve((size_t)BS_ * D_);          // aliased below as pvb
    uint16_t* hb    = carve((size_t)BH_ * S_ * HD_);
    uint16_t* hbT   = carve((size_t)BH_ * HD_ * S_);
    uint16_t* qb    = carve((size_t)BH_ * S_ * HD_);
    uint16_t* pvb   = xb;   // live ranges disjoint: xb dead after k_gemm_in

    hipLaunchKernelGGL(k_prep, dim3(2048), dim3(256), 0, stream,
                       W_in, W_out, W_attn, x, WtIn, WtOut, WtA, xb);
    hipLaunchKernelGGL(k_gemm_in, dim3(2048), dim3(256), 0, stream,
                       xb, WtIn, b_in, hb);
    hipLaunchKernelGGL(k_transpose, dim3(32, 64), dim3(256), 0, stream, hb, hbT);
    hipLaunchKernelGGL(k_gemm_q, dim3(32, 64), dim3(256), 0, stream, hb, WtA, qb);
    hipLaunchKernelGGL(k_attn_fused, dim3(2048), dim3(256), 0, stream,
                       qb, hb, hbT, w_out, pvb);
    hipLaunchKernelGGL(k_gemm_out, dim3(2048), dim3(256), 0, stream,
                       pvb, WtOut, b_out, out);
}

// Round 7
// 756.704 us; speedup vs baseline: 2.0582x; 2.0582x over previous
//
#include <hip/hip_runtime.h>
#include <hip/hip_bf16.h>
#include <stdint.h>

#define DEV __device__ __forceinline__

constexpr int B_ = 4, S_ = 2048, D_ = 1024, H_ = 16, HD_ = 64;
constexpr int BH_ = B_ * H_;   // 64
constexpr int BS_ = B_ * S_;   // 8192

typedef __attribute__((ext_vector_type(8))) short bf16x8;
typedef __attribute__((ext_vector_type(4))) float f32x4;

// log2(e)/64 : scores*SCL fed to exp2 == exp(scores/64)
constexpr float SCL = 0.022542110013890053f;

DEV float fast_exp2(float x) { return __builtin_amdgcn_exp2f(x); }

DEV uint16_t f2bf(float f) {
    union { float f; uint32_t u; } v; v.f = f;
    return (uint16_t)((v.u + 0x7fffu + ((v.u >> 16) & 1u)) >> 16);
}

DEV uint16_t f2bf_fast(float f) {
    __hip_bfloat16 h = __float2bfloat16(f);
    uint16_t u; __builtin_memcpy(&u, &h, 2);
    return u;
}

DEV f32x4 mfma16(bf16x8 a, bf16x8 b, f32x4 c) {
    return __builtin_amdgcn_mfma_f32_16x16x32_bf16(a, b, c, 0, 0, 0);
}

// ---------------------------------------------------------------------------
// Prep: bf16-transpose weights + bf16 convert x.
// ---------------------------------------------------------------------------
__global__ __launch_bounds__(256) void k_prep(
    const float* __restrict__ Win, const float* __restrict__ Wout,
    const float* __restrict__ Wa, const float* __restrict__ x,
    uint16_t* __restrict__ WtIn, uint16_t* __restrict__ WtOut,
    uint16_t* __restrict__ WtA, uint16_t* __restrict__ xb) {
    int stride = gridDim.x * blockDim.x;
    int idx = blockIdx.x * blockDim.x + threadIdx.x;
    for (int i = idx; i < BS_ * D_ / 4; i += stride) {
        float4 v = reinterpret_cast<const float4*>(x)[i];
        ushort4 o;
        o.x = f2bf(v.x); o.y = f2bf(v.y); o.z = f2bf(v.z); o.w = f2bf(v.w);
        reinterpret_cast<ushort4*>(xb)[i] = o;
    }
    for (int i = idx; i < D_ * D_; i += stride) {
        int n = i / D_, k = i % D_;
        WtIn[i]  = f2bf(Win[(size_t)k * D_ + n]);
        WtOut[i] = f2bf(Wout[(size_t)k * D_ + n]);
    }
    for (int i = idx; i < H_ * HD_ * HD_; i += stride) {
        int h = i / (HD_ * HD_);
        int r = i % (HD_ * HD_);
        int e = r / HD_, d = r % HD_;
        WtA[i] = f2bf(Wa[((size_t)h * HD_ + d) * HD_ + e]);
    }
}

// ---------------------------------------------------------------------------
// in_proj: h = xb @ W_in + b_in   (M=8192, N=1024, K=1024)
// 1-D grid 2048, XCD-swizzled: XCD x owns col-panels {2x,2x+1} (B-panel L2).
// ---------------------------------------------------------------------------
__global__ __launch_bounds__(256) void k_gemm_in(
    const uint16_t* __restrict__ xb, const uint16_t* __restrict__ WtIn,
    const float* __restrict__ b_in, uint16_t* __restrict__ hb) {
    const int wave = threadIdx.x >> 6, lane = threadIdx.x & 63;
    const int lhi = lane >> 4, llo = lane & 15;
    const int L = blockIdx.x, xcd = L & 7, slot = L >> 3;
    const int col0 = ((xcd << 1) | (slot & 1)) * 64;
    const int row0 = (slot >> 1) * 64 + wave * 16;

    f32x4 acc[4] = {};
    const uint16_t* xrow = xb + (size_t)(row0 + llo) * D_;
    for (int kc = 0; kc < D_ / 32; ++kc) {
        const int k0 = kc * 32 + lhi * 8;
        bf16x8 a = *reinterpret_cast<const bf16x8*>(xrow + k0);
#pragma unroll
        for (int nt = 0; nt < 4; ++nt) {
            const uint16_t* bp = WtIn + (size_t)(col0 + nt * 16 + llo) * D_ + k0;
            bf16x8 b = *reinterpret_cast<const bf16x8*>(bp);
            acc[nt] = mfma16(a, b, acc[nt]);
        }
    }
#pragma unroll
    for (int nt = 0; nt < 4; ++nt) {
        const int c = col0 + nt * 16 + llo;
        const float bias = b_in[c];
        const int bhcol = c >> 6, d = c & 63;
#pragma unroll
        for (int r = 0; r < 4; ++r) {
            const int m = row0 + lhi * 4 + r;
            const int b_ = m >> 11, s = m & 2047;
            hb[((size_t)(b_ * H_ + bhcol) * S_ + s) * HD_ + d] = f2bf(acc[nt][r] + bias);
        }
    }
}

// ---------------------------------------------------------------------------
// Transpose hb [bh][s][d] -> hbT [bh][d][s]
// ---------------------------------------------------------------------------
__global__ __launch_bounds__(256) void k_transpose(
    const uint16_t* __restrict__ hb, uint16_t* __restrict__ hbT) {
    __shared__ uint16_t tile[64][72];
    const int st = blockIdx.x, bh = blockIdx.y;
    const int s0 = st * 64;
    const int t = threadIdx.x;
    {
        const int r = t >> 2, c0 = (t & 3) * 16;
        const uint16_t* src = hb + ((size_t)bh * S_ + s0 + r) * HD_ + c0;
        *reinterpret_cast<bf16x8*>(&tile[r][c0])     = *reinterpret_cast<const bf16x8*>(src);
        *reinterpret_cast<bf16x8*>(&tile[r][c0 + 8]) = *reinterpret_cast<const bf16x8*>(src + 8);
    }
    __syncthreads();
    {
        const int d = t >> 2, c0 = (t & 3) * 16;
        uint16_t tmp[16];
#pragma unroll
        for (int j = 0; j < 16; ++j) tmp[j] = tile[c0 + j][d];
        uint16_t* dst = hbT + ((size_t)bh * HD_ + d) * S_ + s0 + c0;
        *reinterpret_cast<bf16x8*>(dst)     = *reinterpret_cast<const bf16x8*>(tmp);
        *reinterpret_cast<bf16x8*>(dst + 8) = *reinterpret_cast<const bf16x8*>(tmp + 8);
    }
}

// ---------------------------------------------------------------------------
// q-proj: q[bh][s][e] = sum_d h[bh][s][d] * W_attn[h][d][e]
// ---------------------------------------------------------------------------
__global__ __launch_bounds__(256) void k_gemm_q(
    const uint16_t* __restrict__ hb, const uint16_t* __restrict__ WtA,
    uint16_t* __restrict__ qb) {
    const int wave = threadIdx.x >> 6, lane = threadIdx.x & 63;
    const int lhi = lane >> 4, llo = lane & 15;
    const int bh = blockIdx.y;
    const int h = bh & (H_ - 1);
    const int row0 = blockIdx.x * 64 + wave * 16;

    const uint16_t* hrow = hb + ((size_t)bh * S_ + row0 + llo) * HD_;
    f32x4 acc[4] = {};
#pragma unroll
    for (int kc = 0; kc < 2; ++kc) {
        const int k0 = kc * 32 + lhi * 8;
        bf16x8 a = *reinterpret_cast<const bf16x8*>(hrow + k0);
#pragma unroll
        for (int nt = 0; nt < 4; ++nt) {
            bf16x8 b = *reinterpret_cast<const bf16x8*>(
                WtA + ((size_t)h * HD_ + nt * 16 + llo) * HD_ + k0);
            acc[nt] = mfma16(a, b, acc[nt]);
        }
    }
#pragma unroll
    for (int nt = 0; nt < 4; ++nt) {
        const int e = nt * 16 + llo;
#pragma unroll
        for (int r = 0; r < 4; ++r) {
            const int s = row0 + lhi * 4 + r;
            qb[((size_t)bh * S_ + s) * HD_ + e] = f2bf(acc[nt][r]);
        }
    }
}

// ---------------------------------------------------------------------------
// Fused attention v3: direct global loads (L2-resident h per XCD), NO
// barriers (wb is wave-private), 32 q-rows per wave (2 fragment groups ->
// half the load traffic, 2x the independent MFMA chains), 64 t-cols per
// iteration (8 loads + 8 indep 2-MFMA chains in flight), scalar NT stores
// of w straight from acc layout (each instr fully covers 4x64B sectors ->
// no amplification, no L2 pollution).
// Block = 4 waves = 128 q-rows of one bh; grid = 16 rowtiles x 64 bh = 1024.
// ---------------------------------------------------------------------------
__global__ __launch_bounds__(256) void k_attn_fused(
    const uint16_t* __restrict__ qb, const uint16_t* __restrict__ hb,
    const uint16_t* __restrict__ hbT, float* __restrict__ w_out,
    uint16_t* __restrict__ pvb) {
    __shared__ uint16_t wb[4][32 * 72];   // per-wave private w tile (bf16)

    const int tid = threadIdx.x;
    const int wave = tid >> 6, lane = tid & 63;
    const int lhi = lane >> 4, llo = lane & 15;

    // XCD swizzle: XCD x owns bh in [8x, 8x+8)
    const int L = blockIdx.x;
    const int xcd = L & 7, slot = L >> 3;           // slot in [0,128)
    const int bh = (xcd << 3) | (slot >> 4);
    const int row0 = (slot & 15) * 128 + wave * 32; // wave's 32 q-rows

    const uint16_t* hbase  = hb  + (size_t)bh * S_ * HD_;
    const uint16_t* hTbase = hbT + (size_t)bh * HD_ * S_;

    // Q fragments for the 2 row-groups
    bf16x8 a[2][2];
#pragma unroll
    for (int g = 0; g < 2; ++g) {
        const uint16_t* qrow = qb + ((size_t)bh * S_ + row0 + g * 16 + llo) * HD_;
        a[g][0] = *reinterpret_cast<const bf16x8*>(qrow + lhi * 8);
        a[g][1] = *reinterpret_cast<const bf16x8*>(qrow + 32 + lhi * 8);
    }

    // ================= pass 1: row sums of exp =================
    float sume[2][4] = {};
    for (int tch = 0; tch < 32; ++tch) {
        const int t0 = tch * 64;
        bf16x8 b0[4], b1[4];
#pragma unroll
        for (int ct = 0; ct < 4; ++ct) {
            const uint16_t* hrow = hbase + (size_t)(t0 + ct * 16 + llo) * HD_ + lhi * 8;
            b0[ct] = *reinterpret_cast<const bf16x8*>(hrow);
            b1[ct] = *reinterpret_cast<const bf16x8*>(hrow + 32);
        }
#pragma unroll
        for (int g = 0; g < 2; ++g) {
#pragma unroll
            for (int ct = 0; ct < 4; ++ct) {
                f32x4 acc = {};
                acc = mfma16(a[g][0], b0[ct], acc);
                acc = mfma16(a[g][1], b1[ct], acc);
#pragma unroll
                for (int r = 0; r < 4; ++r) sume[g][r] += fast_exp2(acc[r] * SCL);
            }
        }
    }
    float inv[2][4];
#pragma unroll
    for (int g = 0; g < 2; ++g) {
#pragma unroll
        for (int r = 0; r < 4; ++r) {
            float v = sume[g][r];
            v += __shfl_xor(v, 1); v += __shfl_xor(v, 2);
            v += __shfl_xor(v, 4); v += __shfl_xor(v, 8);
            inv[g][r] = 1.0f / v;
        }
    }

    // ================= pass 2: w (NT scalar stores) + PV =================
    f32x4 pv[2][4] = {};
    uint16_t* mywb = &wb[wave][0];
    float* wrow_base = w_out + ((size_t)bh * S_ + row0) * S_;

    for (int tch = 0; tch < 32; ++tch) {
        const int t0 = tch * 64;
        bf16x8 b0[4], b1[4];
#pragma unroll
        for (int ct = 0; ct < 4; ++ct) {
            const uint16_t* hrow = hbase + (size_t)(t0 + ct * 16 + llo) * HD_ + lhi * 8;
            b0[ct] = *reinterpret_cast<const bf16x8*>(hrow);
            b1[ct] = *reinterpret_cast<const bf16x8*>(hrow + 32);
        }
#pragma unroll
        for (int g = 0; g < 2; ++g) {
#pragma unroll
            for (int ct = 0; ct < 4; ++ct) {
                f32x4 acc = {};
                acc = mfma16(a[g][0], b0[ct], acc);
                acc = mfma16(a[g][1], b1[ct], acc);
#pragma unroll
                for (int r = 0; r < 4; ++r) {
                    const int rr = g * 16 + lhi * 4 + r;      // row in wave band
                    const int cc = ct * 16 + llo;             // col in chunk
                    float wv = fast_exp2(acc[r] * SCL) * inv[g][r];
                    // full-sector NT store: 16 consecutive lanes cover 64B
                    __builtin_nontemporal_store(
                        wv, wrow_base + (size_t)rr * S_ + t0 + cc);
                    mywb[rr * 72 + cc] = f2bf_fast(wv);
                }
            }
        }
        // PV: A = wave-private wb (lgkmcnt ordering handled by compiler),
        // B = hbT direct (L2-resident per XCD)
#pragma unroll
        for (int g = 0; g < 2; ++g) {
#pragma unroll
            for (int kk = 0; kk < 2; ++kk) {
                bf16x8 aw = *reinterpret_cast<const bf16x8*>(
                    &mywb[(g * 16 + llo) * 72 + kk * 32 + lhi * 8]);
#pragma unroll
                for (int dt = 0; dt < 4; ++dt) {
                    bf16x8 b = *reinterpret_cast<const bf16x8*>(
                        hTbase + (size_t)(dt * 16 + llo) * S_ + t0 + kk * 32 + lhi * 8);
                    pv[g][dt] = mfma16(aw, b, pv[g][dt]);
                }
            }
        }
    }

    // epilogue: store pv bf16 into [B][S][D] layout
    const int b_ = bh >> 4, h = bh & (H_ - 1);
#pragma unroll
    for (int g = 0; g < 2; ++g) {
#pragma unroll
        for (int dt = 0; dt < 4; ++dt) {
            const int d = dt * 16 + llo;
#pragma unroll
            for (int r = 0; r < 4; ++r) {
                const int s = row0 + g * 16 + lhi * 4 + r;
                pvb[((size_t)(b_ * S_ + s)) * D_ + h * HD_ + d] = f2bf(pv[g][dt][r]);
            }
        }
    }
}

// ---------------------------------------------------------------------------
// out_proj: out = pv @ W_out + b_out  (fp32 out, XCD swizzle)
// ---------------------------------------------------------------------------
__global__ __launch_bounds__(256) void k_gemm_out(
    const uint16_t* __restrict__ pvb, const uint16_t* __restrict__ WtOut,
    const float* __restrict__ b_out, float* __restrict__ out) {
    const int wave = threadIdx.x >> 6, lane = threadIdx.x & 63;
    const int lhi = lane >> 4, llo = lane & 15;
    const int L = blockIdx.x, xcd = L & 7, slot = L >> 3;
    const int col0 = ((xcd << 1) | (slot & 1)) * 64;
    const int row0 = (slot >> 1) * 64 + wave * 16;

    const uint16_t* prow = pvb + (size_t)(row0 + llo) * D_;
    f32x4 acc[4] = {};
    for (int kc = 0; kc < D_ / 32; ++kc) {
        const int k0 = kc * 32 + lhi * 8;
        bf16x8 a = *reinterpret_cast<const bf16x8*>(prow + k0);
#pragma unroll
        for (int nt = 0; nt < 4; ++nt) {
            bf16x8 b = *reinterpret_cast<const bf16x8*>(
                WtOut + (size_t)(col0 + nt * 16 + llo) * D_ + k0);
            acc[nt] = mfma16(a, b, acc[nt]);
        }
    }
#pragma unroll
    for (int nt = 0; nt < 4; ++nt) {
        const int c = col0 + nt * 16 + llo;
        const float bias = b_out[c];
#pragma unroll
        for (int r = 0; r < 4; ++r) {
            out[(size_t)(row0 + lhi * 4 + r) * D_ + c] = acc[nt][r] + bias;
        }
    }
}

// ---------------------------------------------------------------------------
extern "C" void kernel_launch(void* const* d_in, const int* in_sizes, int n_in,
                              void* d_out, int out_size, void* d_ws, size_t ws_size,
                              hipStream_t stream) {
    const float* x      = (const float*)d_in[0];
    const float* W_attn = (const float*)d_in[1];
    const float* W_in   = (const float*)d_in[2];
    const float* b_in   = (const float*)d_in[3];
    const float* W_out  = (const float*)d_in[4];
    const float* b_out  = (const float*)d_in[5];

    float* out   = (float*)d_out;                       // [B,S,D]
    float* w_out = out + (size_t)BS_ * D_;              // [B,H,S,S]

    uint8_t* ws = (uint8_t*)d_ws;
    auto carve = [&](size_t elems) {
        uint16_t* p = (uint16_t*)ws;
        ws += ((elems * sizeof(uint16_t) + 255) / 256) * 256;
        return p;
    };
    uint16_t* WtIn  = carve((size_t)D_ * D_);
    uint16_t* WtOut = carve((size_t)D_ * D_);
    uint16_t* WtA   = carve((size_t)H_ * HD_ * HD_);
    uint16_t* xb    = carve((size_t)BS_ * D_);          // aliased below as pvb
    uint16_t* hb    = carve((size_t)BH_ * S_ * HD_);
    uint16_t* hbT   = carve((size_t)BH_ * HD_ * S_);
    uint16_t* qb    = carve((size_t)BH_ * S_ * HD_);
    uint16_t* pvb   = xb;   // live ranges disjoint: xb dead after k_gemm_in

    hipLaunchKernelGGL(k_prep, dim3(2048), dim3(256), 0, stream,
                       W_in, W_out, W_attn, x, WtIn, WtOut, WtA, xb);
    hipLaunchKernelGGL(k_gemm_in, dim3(2048), dim3(256), 0, stream,
                       xb, WtIn, b_in, hb);
    hipLaunchKernelGGL(k_transpose, dim3(32, 64), dim3(256), 0, stream, hb, hbT);
    hipLaunchKernelGGL(k_gemm_q, dim3(32, 64), dim3(256), 0, stream, hb, WtA, qb);
    hipLaunchKernelGGL(k_attn_fused, dim3(1024), dim3(256), 0, stream,
                       qb, hb, hbT, w_out, pvb);
    hipLaunchKernelGGL(k_gemm_out, dim3(2048), dim3(256), 0, stream,
                       pvb, WtOut, b_out, out);
}

// Round 8
// 712.234 us; speedup vs baseline: 2.1868x; 1.0624x over previous
//
#include <hip/hip_runtime.h>
#include <hip/hip_bf16.h>
#include <stdint.h>

#define DEV __device__ __forceinline__

constexpr int B_ = 4, S_ = 2048, D_ = 1024, H_ = 16, HD_ = 64;
constexpr int BH_ = B_ * H_;   // 64
constexpr int BS_ = B_ * S_;   // 8192

typedef __attribute__((ext_vector_type(8))) short bf16x8;
typedef __attribute__((ext_vector_type(4))) float f32x4;

// log2(e)/64 : scores*SCL fed to exp2 == exp(scores/64)
constexpr float SCL = 0.022542110013890053f;

DEV float fast_exp2(float x) { return __builtin_amdgcn_exp2f(x); }

DEV uint16_t f2bf(float f) {
    union { float f; uint32_t u; } v; v.f = f;
    return (uint16_t)((v.u + 0x7fffu + ((v.u >> 16) & 1u)) >> 16);
}

DEV uint16_t f2bf_fast(float f) {
    __hip_bfloat16 h = __float2bfloat16(f);
    uint16_t u; __builtin_memcpy(&u, &h, 2);
    return u;
}

DEV f32x4 mfma16(bf16x8 a, bf16x8 b, f32x4 c) {
    return __builtin_amdgcn_mfma_f32_16x16x32_bf16(a, b, c, 0, 0, 0);
}

// ---------------------------------------------------------------------------
// Prep: bf16-transpose weights + bf16 convert x.
// ---------------------------------------------------------------------------
__global__ __launch_bounds__(256) void k_prep(
    const float* __restrict__ Win, const float* __restrict__ Wout,
    const float* __restrict__ Wa, const float* __restrict__ x,
    uint16_t* __restrict__ WtIn, uint16_t* __restrict__ WtOut,
    uint16_t* __restrict__ WtA, uint16_t* __restrict__ xb) {
    int stride = gridDim.x * blockDim.x;
    int idx = blockIdx.x * blockDim.x + threadIdx.x;
    for (int i = idx; i < BS_ * D_ / 4; i += stride) {
        float4 v = reinterpret_cast<const float4*>(x)[i];
        ushort4 o;
        o.x = f2bf(v.x); o.y = f2bf(v.y); o.z = f2bf(v.z); o.w = f2bf(v.w);
        reinterpret_cast<ushort4*>(xb)[i] = o;
    }
    for (int i = idx; i < D_ * D_; i += stride) {
        int n = i / D_, k = i % D_;
        WtIn[i]  = f2bf(Win[(size_t)k * D_ + n]);
        WtOut[i] = f2bf(Wout[(size_t)k * D_ + n]);
    }
    for (int i = idx; i < H_ * HD_ * HD_; i += stride) {
        int h = i / (HD_ * HD_);
        int r = i % (HD_ * HD_);
        int e = r / HD_, d = r % HD_;
        WtA[i] = f2bf(Wa[((size_t)h * HD_ + d) * HD_ + e]);
    }
}

// ---------------------------------------------------------------------------
// Fused projection: one block = one (b, head, 64-row s-tile).
//   1) h-tile = x @ W_in + b_in  (64x64, K=1024, 32 MFMA/wave)
//   2) write hb bf16 [bh][s][d]; stage bf16 h-tile in LDS
//   3) q-tile = h-tile @ W_attn[h]  (K=64, 8 MFMA/wave) -> qb
//   4) transpose LDS tile -> hbT [bh][d][s]
// Replaces k_gemm_in + k_transpose + k_gemm_q (saves 2 launches + 67 MB).
// XCD swizzle: col-panel (= head) locality for WtIn B-panels.
// ---------------------------------------------------------------------------
__global__ __launch_bounds__(256) void k_proj(
    const uint16_t* __restrict__ xb, const uint16_t* __restrict__ WtIn,
    const float* __restrict__ b_in, const uint16_t* __restrict__ WtA,
    uint16_t* __restrict__ hb, uint16_t* __restrict__ hbT,
    uint16_t* __restrict__ qb) {
    __shared__ uint16_t ht[64][72];
    const int tid = threadIdx.x;
    const int wave = tid >> 6, lane = tid & 63;
    const int lhi = lane >> 4, llo = lane & 15;
    const int L = blockIdx.x, xcd = L & 7, slot = L >> 3;
    const int col0 = ((xcd << 1) | (slot & 1)) * 64;
    const int row0 = (slot >> 1) * 64;
    const int wrow = wave * 16;

    // ---- 1) in_proj ----
    f32x4 acc[4] = {};
    const uint16_t* xrow = xb + (size_t)(row0 + wrow + llo) * D_;
    for (int kc = 0; kc < D_ / 32; ++kc) {
        const int k0 = kc * 32 + lhi * 8;
        bf16x8 a = *reinterpret_cast<const bf16x8*>(xrow + k0);
#pragma unroll
        for (int nt = 0; nt < 4; ++nt) {
            bf16x8 b = *reinterpret_cast<const bf16x8*>(
                WtIn + (size_t)(col0 + nt * 16 + llo) * D_ + k0);
            acc[nt] = mfma16(a, b, acc[nt]);
        }
    }

    const int head = (col0 >> 6) & (H_ - 1);
    const int bh = ((row0 >> 11) << 4) | head;
    const int s0 = row0 & (S_ - 1);

    // ---- 2) write hb + stage LDS ----
#pragma unroll
    for (int nt = 0; nt < 4; ++nt) {
        const int c = col0 + nt * 16 + llo;
        const float bias = b_in[c];
        const int d = c & 63;
#pragma unroll
        for (int r = 0; r < 4; ++r) {
            const int rr = wrow + lhi * 4 + r;
            const uint16_t u = f2bf(acc[nt][r] + bias);
            hb[((size_t)bh * S_ + s0 + rr) * HD_ + d] = u;
            ht[rr][d] = u;
        }
    }
    __syncthreads();

    // ---- 3) q-proj from LDS tile ----
    f32x4 qa[4] = {};
#pragma unroll
    for (int kc = 0; kc < 2; ++kc) {
        const int k0 = kc * 32 + lhi * 8;
        bf16x8 a = *reinterpret_cast<const bf16x8*>(&ht[wrow + llo][k0]);
#pragma unroll
        for (int nt = 0; nt < 4; ++nt) {
            bf16x8 b = *reinterpret_cast<const bf16x8*>(
                WtA + ((size_t)head * HD_ + nt * 16 + llo) * HD_ + k0);
            qa[nt] = mfma16(a, b, qa[nt]);
        }
    }
#pragma unroll
    for (int nt = 0; nt < 4; ++nt) {
        const int e = nt * 16 + llo;
#pragma unroll
        for (int r = 0; r < 4; ++r) {
            const int s = s0 + wrow + lhi * 4 + r;
            qb[((size_t)bh * S_ + s) * HD_ + e] = f2bf(qa[nt][r]);
        }
    }

    // ---- 4) transpose -> hbT ----
    {
        const int d = tid >> 2, c0 = (tid & 3) * 16;
        uint16_t tmp[16];
#pragma unroll
        for (int j = 0; j < 16; ++j) tmp[j] = ht[c0 + j][d];
        uint16_t* dst = hbT + ((size_t)bh * HD_ + d) * S_ + s0 + c0;
        *reinterpret_cast<bf16x8*>(dst)     = *reinterpret_cast<const bf16x8*>(tmp);
        *reinterpret_cast<bf16x8*>(dst + 8) = *reinterpret_cast<const bf16x8*>(tmp + 8);
    }
}

// ---------------------------------------------------------------------------
// Fused attention v4: v3 structure (direct L2-resident loads, no barriers,
// wave-private wb, scalar NT w stores) + register ping-pong prefetch of the
// next 64-col h chunk in both passes (hides L2 latency under MFMA+exp).
// Block = 4 waves = 128 q-rows of one bh; grid = 64 bh x 16 slots = 1024.
// ---------------------------------------------------------------------------
__global__ __launch_bounds__(256) void k_attn_fused(
    const uint16_t* __restrict__ qb, const uint16_t* __restrict__ hb,
    const uint16_t* __restrict__ hbT, float* __restrict__ w_out,
    uint16_t* __restrict__ pvb) {
    __shared__ uint16_t wb[4][32 * 72];   // per-wave private w tile (bf16)

    const int tid = threadIdx.x;
    const int wave = tid >> 6, lane = tid & 63;
    const int lhi = lane >> 4, llo = lane & 15;

    // XCD swizzle: XCD x owns bh in [8x, 8x+8)
    const int L = blockIdx.x;
    const int xcd = L & 7, slot = L >> 3;           // slot in [0,128)
    const int bh = (xcd << 3) | (slot >> 4);
    const int row0 = (slot & 15) * 128 + wave * 32; // wave's 32 q-rows

    const uint16_t* hbase  = hb  + (size_t)bh * S_ * HD_;
    const uint16_t* hTbase = hbT + (size_t)bh * HD_ * S_;

    // Q fragments for the 2 row-groups
    bf16x8 a[2][2];
#pragma unroll
    for (int g = 0; g < 2; ++g) {
        const uint16_t* qrow = qb + ((size_t)bh * S_ + row0 + g * 16 + llo) * HD_;
        a[g][0] = *reinterpret_cast<const bf16x8*>(qrow + lhi * 8);
        a[g][1] = *reinterpret_cast<const bf16x8*>(qrow + 32 + lhi * 8);
    }

    auto loadh = [&](int tch, bf16x8 (&b0)[4], bf16x8 (&b1)[4]) {
        const int t0 = tch * 64;
#pragma unroll
        for (int ct = 0; ct < 4; ++ct) {
            const uint16_t* hrow =
                hbase + (size_t)(t0 + ct * 16 + llo) * HD_ + lhi * 8;
            b0[ct] = *reinterpret_cast<const bf16x8*>(hrow);
            b1[ct] = *reinterpret_cast<const bf16x8*>(hrow + 32);
        }
    };

    // ================= pass 1: row sums of exp =================
    float sume[2][4] = {};
    auto p1 = [&](bf16x8 (&b0)[4], bf16x8 (&b1)[4]) {
#pragma unroll
        for (int g = 0; g < 2; ++g) {
#pragma unroll
            for (int ct = 0; ct < 4; ++ct) {
                f32x4 acc = {};
                acc = mfma16(a[g][0], b0[ct], acc);
                acc = mfma16(a[g][1], b1[ct], acc);
#pragma unroll
                for (int r = 0; r < 4; ++r) sume[g][r] += fast_exp2(acc[r] * SCL);
            }
        }
    };
    {
        bf16x8 A0[4], A1[4], B0[4], B1[4];
        loadh(0, A0, A1);
        for (int tch = 0; tch < 32; tch += 2) {
            loadh(tch + 1, B0, B1);
            p1(A0, A1);
            if (tch + 2 < 32) loadh(tch + 2, A0, A1);
            p1(B0, B1);
        }
    }
    float inv[2][4];
#pragma unroll
    for (int g = 0; g < 2; ++g) {
#pragma unroll
        for (int r = 0; r < 4; ++r) {
            float v = sume[g][r];
            v += __shfl_xor(v, 1); v += __shfl_xor(v, 2);
            v += __shfl_xor(v, 4); v += __shfl_xor(v, 8);
            inv[g][r] = 1.0f / v;
        }
    }

    // ================= pass 2: w (NT scalar stores) + PV =================
    f32x4 pv[2][4] = {};
    uint16_t* mywb = &wb[wave][0];
    float* wrow_base = w_out + ((size_t)bh * S_ + row0) * S_;

    auto p2 = [&](int tch, bf16x8 (&b0)[4], bf16x8 (&b1)[4]) {
        const int t0 = tch * 64;
#pragma unroll
        for (int g = 0; g < 2; ++g) {
#pragma unroll
            for (int ct = 0; ct < 4; ++ct) {
                f32x4 acc = {};
                acc = mfma16(a[g][0], b0[ct], acc);
                acc = mfma16(a[g][1], b1[ct], acc);
#pragma unroll
                for (int r = 0; r < 4; ++r) {
                    const int rr = g * 16 + lhi * 4 + r;      // row in wave band
                    const int cc = ct * 16 + llo;             // col in chunk
                    float wv = fast_exp2(acc[r] * SCL) * inv[g][r];
                    // full-sector NT store: 16 consecutive lanes cover 64B
                    __builtin_nontemporal_store(
                        wv, wrow_base + (size_t)rr * S_ + t0 + cc);
                    mywb[rr * 72 + cc] = f2bf_fast(wv);
                }
            }
        }
        // PV: A = wave-private wb, B = hbT direct (L2-resident per XCD)
#pragma unroll
        for (int g = 0; g < 2; ++g) {
#pragma unroll
            for (int kk = 0; kk < 2; ++kk) {
                bf16x8 aw = *reinterpret_cast<const bf16x8*>(
                    &mywb[(g * 16 + llo) * 72 + kk * 32 + lhi * 8]);
#pragma unroll
                for (int dt = 0; dt < 4; ++dt) {
                    bf16x8 b = *reinterpret_cast<const bf16x8*>(
                        hTbase + (size_t)(dt * 16 + llo) * S_ + t0 + kk * 32 + lhi * 8);
                    pv[g][dt] = mfma16(aw, b, pv[g][dt]);
                }
            }
        }
    };
    {
        bf16x8 A0[4], A1[4], B0[4], B1[4];
        loadh(0, A0, A1);
        for (int tch = 0; tch < 32; tch += 2) {
            loadh(tch + 1, B0, B1);
            p2(tch, A0, A1);
            if (tch + 2 < 32) loadh(tch + 2, A0, A1);
            p2(tch + 1, B0, B1);
        }
    }

    // epilogue: store pv bf16 into [B][S][D] layout
    const int b_ = bh >> 4, h = bh & (H_ - 1);
#pragma unroll
    for (int g = 0; g < 2; ++g) {
#pragma unroll
        for (int dt = 0; dt < 4; ++dt) {
            const int d = dt * 16 + llo;
#pragma unroll
            for (int r = 0; r < 4; ++r) {
                const int s = row0 + g * 16 + lhi * 4 + r;
                pvb[((size_t)(b_ * S_ + s)) * D_ + h * HD_ + d] = f2bf(pv[g][dt][r]);
            }
        }
    }
}

// ---------------------------------------------------------------------------
// out_proj: out = pv @ W_out + b_out  (fp32 out, XCD swizzle)
// ---------------------------------------------------------------------------
__global__ __launch_bounds__(256) void k_gemm_out(
    const uint16_t* __restrict__ pvb, const uint16_t* __restrict__ WtOut,
    const float* __restrict__ b_out, float* __restrict__ out) {
    const int wave = threadIdx.x >> 6, lane = threadIdx.x & 63;
    const int lhi = lane >> 4, llo = lane & 15;
    const int L = blockIdx.x, xcd = L & 7, slot = L >> 3;
    const int col0 = ((xcd << 1) | (slot & 1)) * 64;
    const int row0 = (slot >> 1) * 64 + wave * 16;

    const uint16_t* prow = pvb + (size_t)(row0 + llo) * D_;
    f32x4 acc[4] = {};
    for (int kc = 0; kc < D_ / 32; ++kc) {
        const int k0 = kc * 32 + lhi * 8;
        bf16x8 a = *reinterpret_cast<const bf16x8*>(prow + k0);
#pragma unroll
        for (int nt = 0; nt < 4; ++nt) {
            bf16x8 b = *reinterpret_cast<const bf16x8*>(
                WtOut + (size_t)(col0 + nt * 16 + llo) * D_ + k0);
            acc[nt] = mfma16(a, b, acc[nt]);
        }
    }
#pragma unroll
    for (int nt = 0; nt < 4; ++nt) {
        const int c = col0 + nt * 16 + llo;
        const float bias = b_out[c];
#pragma unroll
        for (int r = 0; r < 4; ++r) {
            out[(size_t)(row0 + lhi * 4 + r) * D_ + c] = acc[nt][r] + bias;
        }
    }
}

// ---------------------------------------------------------------------------
extern "C" void kernel_launch(void* const* d_in, const int* in_sizes, int n_in,
                              void* d_out, int out_size, void* d_ws, size_t ws_size,
                              hipStream_t stream) {
    const float* x      = (const float*)d_in[0];
    const float* W_attn = (const float*)d_in[1];
    const float* W_in   = (const float*)d_in[2];
    const float* b_in   = (const float*)d_in[3];
    const float* W_out  = (const float*)d_in[4];
    const float* b_out  = (const float*)d_in[5];

    float* out   = (float*)d_out;                       // [B,S,D]
    float* w_out = out + (size_t)BS_ * D_;              // [B,H,S,S]

    uint8_t* ws = (uint8_t*)d_ws;
    auto carve = [&](size_t elems) {
        uint16_t* p = (uint16_t*)ws;
        ws += ((elems * sizeof(uint16_t) + 255) / 256) * 256;
        return p;
    };
    uint16_t* WtIn  = carve((size_t)D_ * D_);
    uint16_t* WtOut = carve((size_t)D_ * D_);
    uint16_t* WtA   = carve((size_t)H_ * HD_ * HD_);
    uint16_t* xb    = carve((size_t)BS_ * D_);          // aliased below as pvb
    uint16_t* hb    = carve((size_t)BH_ * S_ * HD_);
    uint16_t* hbT   = carve((size_t)BH_ * HD_ * S_);
    uint16_t* qb    = carve((size_t)BH_ * S_ * HD_);
    uint16_t* pvb   = xb;   // live ranges disjoint: xb dead after k_proj

    hipLaunchKernelGGL(k_prep, dim3(2048), dim3(256), 0, stream,
                       W_in, W_out, W_attn, x, WtIn, WtOut, WtA, xb);
    hipLaunchKernelGGL(k_proj, dim3(2048), dim3(256), 0, stream,
                       xb, WtIn, b_in, WtA, hb, hbT, qb);
    hipLaunchKernelGGL(k_attn_fused, dim3(1024), dim3(256), 0, stream,
                       qb, hb, hbT, w_out, pvb);
    hipLaunchKernelGGL(k_gemm_out, dim3(2048), dim3(256), 0, stream,
                       pvb, WtOut, b_out, out);
}